// Round 3
// baseline (977.714 us; speedup 1.0000x reference)
//
#include <hip/hip_runtime.h>
#include <hip/hip_bf16.h>

// CausalSelfAttention: B=8 T=1024 C=2048 NH=16 HD=128.
// I/O is FP32 (per reference); compute is bf16 MFMA with fp32 accum
// (threshold is 2% of max|ref| -> bf16 compute permitted).
// Buffers: ws[0..32MiB) = x_bf16, later y_bf16 (head-major);
//          ws[32..64MiB) = Q bf16; d_out = K bf16 | V bf16 until proj GEMM
//          overwrites it with the fp32 result (K/V dead by then).

typedef unsigned short u16;
typedef __bf16 bf16x8 __attribute__((ext_vector_type(8)));
typedef float f32x4 __attribute__((ext_vector_type(4)));

#define B_ 8
#define T_ 1024
#define C_ 2048
#define NH 16
#define HD 128
#define BH (B_*NH)

__device__ __forceinline__ u16 f2b(float f){
  __bf16 h = (__bf16)f; return __builtin_bit_cast(u16, h);   // RNE
}
__device__ __forceinline__ bf16x8 ldfrag(const u16* p){
  uint4 u = *(const uint4*)p; return __builtin_bit_cast(bf16x8, u);
}

// ---------------- fp32 -> bf16 pack, n4 = n/4 ------------------------------
__global__ __launch_bounds__(256) void cvt_bf16(
    const float4* __restrict__ in, ushort4* __restrict__ outp, int n4)
{
  int i = blockIdx.x*256 + threadIdx.x;
  const int stride = gridDim.x*256;
  for (; i < n4; i += stride){
    float4 f = in[i];
    ushort4 o; o.x = f2b(f.x); o.y = f2b(f.y); o.z = f2b(f.z); o.w = f2b(f.w);
    outp[i] = o;
  }
}

// ---------------- QKV GEMM: A = x_bf16 [8192][2048]; W fp32 [2048][6144]
// (cvt+transposed into Bs[n][k] during staging). Scatter Q/K/V [BH][T][HD].
__global__ __launch_bounds__(256,2) void gemm_qkv(
    const u16* __restrict__ A, const float* __restrict__ W, const float* __restrict__ bias,
    u16* __restrict__ qb, u16* __restrict__ kb, u16* __restrict__ vb)
{
  __shared__ u16 As[128*32];                   // As[m][k]
  __shared__ u16 Bs[128*32];                   // Bs[n][k]
  const int t = threadIdx.x;
  const int bx = blockIdx.x, by = blockIdx.y;
  const int lane = t & 63, wv = t >> 6;
  const int lq = lane >> 4, ln = lane & 15;
  const int wm = wv >> 1, wn = wv & 1;

  const int ar = t >> 1, ah = t & 1;           // A stage: 2 thr/row, 16 elems
  const u16* Ap = A + (size_t)(by*128 + ar)*2048 + ah*16;
  u16* AsW = &As[ar*32 + ah*16];

  const int br = t & 31, bc = (t >> 5)*16;     // W stage: k-row br, col chunk bc
  const float* Wp = W + (size_t)br*6144 + bx*128 + bc;

  const f32x4 fz = {0.f,0.f,0.f,0.f};
  f32x4 acc[4][4];
#pragma unroll
  for (int i=0;i<4;i++)
#pragma unroll
    for (int j=0;j<4;j++) acc[i][j] = fz;

  for (int kt = 0; kt < 64; ++kt){
    uint4 a0 = *(const uint4*)(Ap);
    uint4 a1 = *(const uint4*)(Ap + 8);
    float4 w0 = *(const float4*)(Wp);
    float4 w1 = *(const float4*)(Wp + 4);
    float4 w2 = *(const float4*)(Wp + 8);
    float4 w3 = *(const float4*)(Wp + 12);
    Ap += 32; Wp += (size_t)32*6144;
    __syncthreads();
    *(uint4*)(AsW) = a0; *(uint4*)(AsW + 8) = a1;
    Bs[(bc+ 0)*32+br]=f2b(w0.x); Bs[(bc+ 1)*32+br]=f2b(w0.y);
    Bs[(bc+ 2)*32+br]=f2b(w0.z); Bs[(bc+ 3)*32+br]=f2b(w0.w);
    Bs[(bc+ 4)*32+br]=f2b(w1.x); Bs[(bc+ 5)*32+br]=f2b(w1.y);
    Bs[(bc+ 6)*32+br]=f2b(w1.z); Bs[(bc+ 7)*32+br]=f2b(w1.w);
    Bs[(bc+ 8)*32+br]=f2b(w2.x); Bs[(bc+ 9)*32+br]=f2b(w2.y);
    Bs[(bc+10)*32+br]=f2b(w2.z); Bs[(bc+11)*32+br]=f2b(w2.w);
    Bs[(bc+12)*32+br]=f2b(w3.x); Bs[(bc+13)*32+br]=f2b(w3.y);
    Bs[(bc+14)*32+br]=f2b(w3.z); Bs[(bc+15)*32+br]=f2b(w3.w);
    __syncthreads();
    bf16x8 af[4], bf[4];
#pragma unroll
    for (int i=0;i<4;i++) af[i] = ldfrag(&As[(wm*64 + i*16 + ln)*32 + lq*8]);
#pragma unroll
    for (int j=0;j<4;j++) bf[j] = ldfrag(&Bs[(wn*64 + j*16 + ln)*32 + lq*8]);
#pragma unroll
    for (int i=0;i<4;i++)
#pragma unroll
      for (int j=0;j<4;j++)
        acc[i][j] = __builtin_amdgcn_mfma_f32_16x16x32_bf16(af[i], bf[j], acc[i][j], 0,0,0);
  }

  const int tensor = bx >> 4, h = bx & 15, b = by >> 3, t0 = (by & 7)*128;
  u16* tb = tensor==0 ? qb : (tensor==1 ? kb : vb);
  u16* op = tb + ((size_t)(b*NH + h)*T_ + t0)*HD;
#pragma unroll
  for (int j=0;j<4;j++){
    const float bv = bias[bx*128 + wn*64 + j*16 + ln];
    const int n = wn*64 + j*16 + ln;
#pragma unroll
    for (int i=0;i<4;i++){
      const int m0 = wm*64 + i*16 + lq*4;      // C/D: row = quad*4 + reg
#pragma unroll
      for (int r=0;r<4;r++)
        op[(size_t)(m0 + r)*HD + n] = f2b(acc[i][j][r] + bv);
    }
  }
}

// ---------------- proj GEMM: A = y bf16 head-major [BH][T][HD]; W fp32; out fp32.
__global__ __launch_bounds__(256,2) void gemm_proj(
    const u16* __restrict__ Y, const float* __restrict__ W, const float* __restrict__ bias,
    float* __restrict__ outp)
{
  __shared__ u16 As[128*32];
  __shared__ u16 Bs[128*32];
  const int t = threadIdx.x;
  const int bx = blockIdx.x, by = blockIdx.y;
  const int lane = t & 63, wv = t >> 6;
  const int lq = lane >> 4, ln = lane & 15;
  const int wm = wv >> 1, wn = wv & 1;

  const int ar = t >> 1, ah = t & 1;
  const int m = by*128 + ar, b = m >> 10, tt = m & 1023;
  const size_t rowbase = ((size_t)(b*NH)*T_ + tt)*HD;
  u16* AsW = &As[ar*32 + ah*16];

  const int br = t & 31, bc = (t >> 5)*16;
  const float* Wp = W + (size_t)br*2048 + bx*128 + bc;

  const f32x4 fz = {0.f,0.f,0.f,0.f};
  f32x4 acc[4][4];
#pragma unroll
  for (int i=0;i<4;i++)
#pragma unroll
    for (int j=0;j<4;j++) acc[i][j] = fz;

  for (int kt = 0; kt < 64; ++kt){
    const int c = kt*32 + ah*16;               // global col in [0,2048)
    const u16* Ap = Y + rowbase + (size_t)(c >> 7)*(T_*HD) + (c & 127);
    uint4 a0 = *(const uint4*)(Ap);
    uint4 a1 = *(const uint4*)(Ap + 8);
    float4 w0 = *(const float4*)(Wp);
    float4 w1 = *(const float4*)(Wp + 4);
    float4 w2 = *(const float4*)(Wp + 8);
    float4 w3 = *(const float4*)(Wp + 12);
    Wp += (size_t)32*2048;
    __syncthreads();
    *(uint4*)(AsW) = a0; *(uint4*)(AsW + 8) = a1;
    Bs[(bc+ 0)*32+br]=f2b(w0.x); Bs[(bc+ 1)*32+br]=f2b(w0.y);
    Bs[(bc+ 2)*32+br]=f2b(w0.z); Bs[(bc+ 3)*32+br]=f2b(w0.w);
    Bs[(bc+ 4)*32+br]=f2b(w1.x); Bs[(bc+ 5)*32+br]=f2b(w1.y);
    Bs[(bc+ 6)*32+br]=f2b(w1.z); Bs[(bc+ 7)*32+br]=f2b(w1.w);
    Bs[(bc+ 8)*32+br]=f2b(w2.x); Bs[(bc+ 9)*32+br]=f2b(w2.y);
    Bs[(bc+10)*32+br]=f2b(w2.z); Bs[(bc+11)*32+br]=f2b(w2.w);
    Bs[(bc+12)*32+br]=f2b(w3.x); Bs[(bc+13)*32+br]=f2b(w3.y);
    Bs[(bc+14)*32+br]=f2b(w3.z); Bs[(bc+15)*32+br]=f2b(w3.w);
    __syncthreads();
    bf16x8 af[4], bf[4];
#pragma unroll
    for (int i=0;i<4;i++) af[i] = ldfrag(&As[(wm*64 + i*16 + ln)*32 + lq*8]);
#pragma unroll
    for (int j=0;j<4;j++) bf[j] = ldfrag(&Bs[(wn*64 + j*16 + ln)*32 + lq*8]);
#pragma unroll
    for (int i=0;i<4;i++)
#pragma unroll
      for (int j=0;j<4;j++)
        acc[i][j] = __builtin_amdgcn_mfma_f32_16x16x32_bf16(af[i], bf[j], acc[i][j], 0,0,0);
  }

  float* op = outp + (size_t)(by*128)*2048 + bx*128;
#pragma unroll
  for (int j=0;j<4;j++){
    const float bv = bias[bx*128 + wn*64 + j*16 + ln];
    const int n = wn*64 + j*16 + ln;
#pragma unroll
    for (int i=0;i<4;i++){
      const int m0 = wm*64 + i*16 + lq*4;
#pragma unroll
      for (int r=0;r<4;r++)
        op[(size_t)(m0 + r)*2048 + n] = acc[i][j][r] + bv;
    }
  }
}

// ---------------- flash attention. q,k,v bf16 [BH][T][HD]; y bf16 [BH][T][HD].
__global__ __launch_bounds__(256,2) void attn_fwd(
    const u16* __restrict__ q, const u16* __restrict__ kk, const u16* __restrict__ vv,
    u16* __restrict__ y)
{
  __shared__ u16 Ks[64*128];                   // [key][d]
  __shared__ u16 Vt[128*64];                   // [d][key]
  __shared__ u16 Ps[4*32*64];                  // per-wave P strip
  const int qt = blockIdx.x, bh = blockIdx.y;
  const int t = threadIdx.x;
  const int lane = t & 63, wv = t >> 6;
  const int lq = lane >> 4, ln = lane & 15;

  bf16x8 qf[2][4];                             // A-frag: m=lane&15, k=quad*8+j
#pragma unroll
  for (int i=0;i<2;i++)
#pragma unroll
    for (int kc=0;kc<4;kc++){
      int qrow = qt*128 + wv*32 + i*16 + ln;
      qf[i][kc] = ldfrag(&q[((size_t)bh*T_ + qrow)*HD + kc*32 + lq*8]);
    }

  const f32x4 fz = {0.f,0.f,0.f,0.f};
  f32x4 o[2][8];
#pragma unroll
  for (int i=0;i<2;i++)
#pragma unroll
    for (int jd=0;jd<8;jd++) o[i][jd] = fz;
  float mi[2][4], li[2][4];
#pragma unroll
  for (int i=0;i<2;i++)
#pragma unroll
    for (int r=0;r<4;r++){ mi[i][r] = -1e30f; li[i][r] = 0.f; }

  const float scale = 0.08838834764831843f;    // 1/sqrt(128)
  const int kr = t & 63, dbase = (t >> 6)*32;  // V-transpose stage mapping
  const int nkt = 2*qt + 2;                    // causal: keys < (qt+1)*128
  for (int kt = 0; kt < nkt; ++kt){
    uint4 kreg[4];
    uint4 vreg[4];
    const uint4* ksrc = (const uint4*)(kk + ((size_t)bh*T_ + kt*64)*HD);
#pragma unroll
    for (int ii=0; ii<4; ++ii) kreg[ii] = ksrc[t + ii*256];
#pragma unroll
    for (int ch=0; ch<4; ++ch)
      vreg[ch] = *(const uint4*)&vv[((size_t)bh*T_ + kt*64 + kr)*HD + dbase + ch*8];
    __syncthreads();                           // prior iter done reading Ks/Vt
    uint4* kdst = (uint4*)Ks;
#pragma unroll
    for (int ii=0; ii<4; ++ii) kdst[t + ii*256] = kreg[ii];
#pragma unroll
    for (int ch=0; ch<4; ++ch){
      const u16* e = (const u16*)&vreg[ch];
#pragma unroll
      for (int j=0; j<8; ++j)
        Vt[(dbase + ch*8 + j)*64 + kr] = e[j];  // banks = kr>>1: 2-way, free
    }
    __syncthreads();

    // S = Q K^T
    f32x4 s[2][4];
#pragma unroll
    for (int i=0;i<2;i++)
#pragma unroll
      for (int j=0;j<4;j++) s[i][j] = fz;
#pragma unroll
    for (int j=0;j<4;j++){
      bf16x8 kf[4];                            // B-frag: n=key, k=d
#pragma unroll
      for (int kc=0;kc<4;kc++) kf[kc] = ldfrag(&Ks[(j*16 + ln)*128 + kc*32 + lq*8]);
#pragma unroll
      for (int i=0;i<2;i++)
#pragma unroll
        for (int kc=0;kc<4;kc++)
          s[i][j] = __builtin_amdgcn_mfma_f32_16x16x32_bf16(qf[i][kc], kf[kc], s[i][j], 0,0,0);
    }

    // scale + causal mask (C/D: row=quad*4+r, col=lane&15)
#pragma unroll
    for (int i=0;i<2;i++)
#pragma unroll
      for (int j=0;j<4;j++)
#pragma unroll
        for (int r=0;r<4;r++){
          int qg = qt*128 + wv*32 + i*16 + lq*4 + r;
          int kg = kt*64 + j*16 + ln;
          float sv = s[i][j][r]*scale;
          s[i][j][r] = (kg > qg) ? -1e30f : sv;
        }

    // online softmax (row = (i,r); 64 cols = 4 j x 16 lanes of same quad)
#pragma unroll
    for (int i=0;i<2;i++)
#pragma unroll
      for (int r=0;r<4;r++){
        float mx = fmaxf(fmaxf(s[i][0][r], s[i][1][r]), fmaxf(s[i][2][r], s[i][3][r]));
        mx = fmaxf(mx, __shfl_xor(mx, 1));
        mx = fmaxf(mx, __shfl_xor(mx, 2));
        mx = fmaxf(mx, __shfl_xor(mx, 4));
        mx = fmaxf(mx, __shfl_xor(mx, 8));
        float mnew = fmaxf(mi[i][r], mx);
        float alpha = __expf(mi[i][r] - mnew);
        float rs = 0.f;
#pragma unroll
        for (int j=0;j<4;j++){
          float p = __expf(s[i][j][r] - mnew);
          s[i][j][r] = p; rs += p;
        }
        rs += __shfl_xor(rs, 1); rs += __shfl_xor(rs, 2);
        rs += __shfl_xor(rs, 4); rs += __shfl_xor(rs, 8);
        li[i][r] = li[i][r]*alpha + rs;
        mi[i][r] = mnew;
#pragma unroll
        for (int jd=0;jd<8;jd++) o[i][jd][r] *= alpha;
      }

    // P: C-layout -> per-wave LDS strip -> A-layout frags
#pragma unroll
    for (int i=0;i<2;i++)
#pragma unroll
      for (int j=0;j<4;j++)
#pragma unroll
        for (int r=0;r<4;r++)
          Ps[wv*2048 + (i*16 + lq*4 + r)*64 + j*16 + ln] = f2b(s[i][j][r]);

    bf16x8 pf[2][2];
#pragma unroll
    for (int i=0;i<2;i++)
#pragma unroll
      for (int kc=0;kc<2;kc++)
        pf[i][kc] = ldfrag(&Ps[wv*2048 + (i*16 + ln)*64 + kc*32 + lq*8]);
#pragma unroll
    for (int jd=0;jd<8;jd++)
#pragma unroll
      for (int kc=0;kc<2;kc++){
        bf16x8 vf = ldfrag(&Vt[(jd*16 + ln)*64 + kc*32 + lq*8]);
#pragma unroll
        for (int i=0;i<2;i++)
          o[i][jd] = __builtin_amdgcn_mfma_f32_16x16x32_bf16(pf[i][kc], vf, o[i][jd], 0,0,0);
      }
  }

  // epilogue: y head-major [BH][T][HD]
#pragma unroll
  for (int i=0;i<2;i++)
#pragma unroll
    for (int r=0;r<4;r++){
      float inv = 1.f / li[i][r];
      int row = qt*128 + wv*32 + i*16 + lq*4 + r;
#pragma unroll
      for (int jd=0;jd<8;jd++)
        y[((size_t)bh*T_ + row)*HD + jd*16 + ln] = f2b(o[i][jd][r] * inv);
    }
}

extern "C" void kernel_launch(void* const* d_in, const int* in_sizes, int n_in,
                              void* d_out, int out_size, void* d_ws, size_t ws_size,
                              hipStream_t stream)
{
  const float* x      = (const float*)d_in[0];   // [8192][2048] fp32
  const float* W_attn = (const float*)d_in[1];   // [2048][6144] fp32
  const float* b_attn = (const float*)d_in[2];   // [6144] fp32
  const float* W_proj = (const float*)d_in[3];   // [2048][2048] fp32
  const float* b_proj = (const float*)d_in[4];   // [2048] fp32
  float* out = (float*)d_out;                    // [8192][2048] fp32

  u16* xb = (u16*)d_ws;                          // x bf16, later y bf16
  u16* qb = xb + (size_t)B_*T_*C_;               // Q bf16
  u16* kb = (u16*)d_out;                         // K bf16 (d_out low half)
  u16* vb = kb + (size_t)BH*T_*HD;               // V bf16 (d_out high half)

  hipLaunchKernelGGL(cvt_bf16, dim3(1024,1,1), dim3(256,1,1), 0, stream,
                     (const float4*)x, (ushort4*)xb, (B_*T_*C_)/4);
  hipLaunchKernelGGL(gemm_qkv, dim3(48,64,1), dim3(256,1,1), 0, stream,
                     xb, W_attn, b_attn, qb, kb, vb);
  hipLaunchKernelGGL(attn_fwd, dim3(8,BH,1), dim3(256,1,1), 0, stream,
                     qb, kb, vb, xb);
  hipLaunchKernelGGL(gemm_proj, dim3(16,64,1), dim3(256,1,1), 0, stream,
                     xb, W_proj, b_proj, out);
}

// Round 5
// 784.578 us; speedup vs baseline: 1.2462x; 1.2462x over previous
//
#include <hip/hip_runtime.h>
#include <hip/hip_bf16.h>

// CausalSelfAttention: B=8 T=1024 C=2048 NH=16 HD=128. FP32 I/O, bf16 MFMA.
// R5 = R4 with pk2 fixed (no bit_cast of __hip_bfloat162).
// W pre-transposed+cvt to bf16 [N][K] in ws; GEMM B-staging (and proj
// A-staging) via global_load_lds dwordx4 (m97 structure). x read as fp32 with
// packed cvt in A-staging.
// ws (64 MiB): Wat^T 24 | Wpt^T 8 | Q 32 (y overwrites Q after attn).
// d_out: K bf16 | V bf16 until proj GEMM overwrites with fp32 result.

typedef unsigned short u16;
typedef __bf16 bf16x8 __attribute__((ext_vector_type(8)));
typedef float f32x4 __attribute__((ext_vector_type(4)));

#define B_ 8
#define T_ 1024
#define C_ 2048
#define NH 16
#define HD 128
#define BH (B_*NH)

__device__ __forceinline__ u16 f2b(float f){
  __bf16 h = (__bf16)f; return __builtin_bit_cast(u16, h);   // RNE
}
__device__ __forceinline__ unsigned pk2(float x, float y){
  return (unsigned)f2b(x) | ((unsigned)f2b(y) << 16);
}
__device__ __forceinline__ bf16x8 ldfrag(const u16* p){
  uint4 u = *(const uint4*)p; return __builtin_bit_cast(bf16x8, u);
}
__device__ __forceinline__ void glds16(const u16* g, const u16* l){
  __builtin_amdgcn_global_load_lds(
      (const __attribute__((address_space(1))) void*)g,
      (__attribute__((address_space(3))) void*)l, 16, 0, 0);
}

// ---------------- W fp32 [R][C] -> bf16 W^T [C][R], 64x64 tiles --------------
__global__ __launch_bounds__(256) void transpose_cvt(
    const float* __restrict__ in, u16* __restrict__ outp, int R, int C)
{
  __shared__ u16 tile[64][65];
  const int t = threadIdx.x;
  const int r0 = blockIdx.y * 64, c0 = blockIdx.x * 64;
#pragma unroll
  for (int ii = 0; ii < 16; ++ii){
    int idx = t + ii*256; int r = idx >> 6, c = idx & 63;
    tile[r][c] = f2b(in[(size_t)(r0 + r)*C + c0 + c]);
  }
  __syncthreads();
#pragma unroll
  for (int ii = 0; ii < 16; ++ii){
    int idx = t + ii*256; int r = idx >> 6, c = idx & 63;
    outp[(size_t)(c0 + r)*R + r0 + c] = tile[c][r];
  }
}

// ---------------- QKV GEMM: A = x fp32 [8192][2048] (cvt in staging);
// B = Wat^T bf16 [6144][2048] via global_load_lds. Scatter Q/K/V [BH][T][HD].
__global__ __launch_bounds__(256,2) void gemm_qkv(
    const float* __restrict__ X, const u16* __restrict__ Wt, const float* __restrict__ bias,
    u16* __restrict__ qb, u16* __restrict__ kb, u16* __restrict__ vb)
{
  __shared__ u16 As[128*32];                   // [m][k]
  __shared__ u16 Bs[128*32];                   // [n][k]
  const int t = threadIdx.x;
  const int bx = blockIdx.x, by = blockIdx.y;
  const int lane = t & 63, wv = t >> 6;
  const int lq = lane >> 4, ln = lane & 15;
  const int wm = wv >> 1, wn = wv & 1;

  const int ar = t >> 1, ah = t & 1;           // A: 2 thr/row, 16 fp32 each
  const float* Ap = X + (size_t)(by*128 + ar)*2048 + ah*16;
  u16* AsW = &As[ar*32 + ah*16];

  // B via glds: pass p chunk c=p*256+t -> row c>>2, k-sub c&3 (8 elems)
  const int c0 = t, c1 = 256 + t;
  const u16* Bp0 = Wt + (size_t)(bx*128 + (c0 >> 2))*2048 + (c0 & 3)*8;
  const u16* Bp1 = Wt + (size_t)(bx*128 + (c1 >> 2))*2048 + (c1 & 3)*8;
  const u16* BsW0 = &Bs[(wv*64)*8];            // wave-uniform LDS bases
  const u16* BsW1 = &Bs[(256 + wv*64)*8];

  const f32x4 fz = {0.f,0.f,0.f,0.f};
  f32x4 acc[4][4];
#pragma unroll
  for (int i=0;i<4;i++)
#pragma unroll
    for (int j=0;j<4;j++) acc[i][j] = fz;

  for (int kt = 0; kt < 64; ++kt){
    float4 a0 = *(const float4*)(Ap);
    float4 a1 = *(const float4*)(Ap + 4);
    float4 a2 = *(const float4*)(Ap + 8);
    float4 a3 = *(const float4*)(Ap + 12);
    Ap += 32;
    __syncthreads();                           // prior iter done reading LDS
    uint4 w0, w1;
    w0.x = pk2(a0.x,a0.y); w0.y = pk2(a0.z,a0.w);
    w0.z = pk2(a1.x,a1.y); w0.w = pk2(a1.z,a1.w);
    w1.x = pk2(a2.x,a2.y); w1.y = pk2(a2.z,a2.w);
    w1.z = pk2(a3.x,a3.y); w1.w = pk2(a3.z,a3.w);
    *(uint4*)(AsW) = w0; *(uint4*)(AsW + 8) = w1;
    glds16(Bp0, BsW0);
    glds16(Bp1, BsW1);
    Bp0 += 32; Bp1 += 32;
    __syncthreads();                           // drains vmcnt (glds) + lgkm
    bf16x8 af[4], bf[4];
#pragma unroll
    for (int i=0;i<4;i++) af[i] = ldfrag(&As[(wm*64 + i*16 + ln)*32 + lq*8]);
#pragma unroll
    for (int j=0;j<4;j++) bf[j] = ldfrag(&Bs[(wn*64 + j*16 + ln)*32 + lq*8]);
#pragma unroll
    for (int i=0;i<4;i++)
#pragma unroll
      for (int j=0;j<4;j++)
        acc[i][j] = __builtin_amdgcn_mfma_f32_16x16x32_bf16(af[i], bf[j], acc[i][j], 0,0,0);
  }

  const int tensor = bx >> 4, h = bx & 15, b = by >> 3, t0 = (by & 7)*128;
  u16* tb = tensor==0 ? qb : (tensor==1 ? kb : vb);
  u16* op = tb + ((size_t)(b*NH + h)*T_ + t0)*HD;
#pragma unroll
  for (int j=0;j<4;j++){
    const float bv = bias[bx*128 + wn*64 + j*16 + ln];
    const int n = wn*64 + j*16 + ln;
#pragma unroll
    for (int i=0;i<4;i++){
      const int m0 = wm*64 + i*16 + lq*4;      // C/D: row = quad*4 + reg
#pragma unroll
      for (int r=0;r<4;r++)
        op[(size_t)(m0 + r)*HD + n] = f2b(acc[i][j][r] + bv);
    }
  }
}

// ---------------- proj GEMM: A = y bf16 head-major [BH][T][HD] (glds);
// B = Wpt^T bf16 [2048][2048] (glds); out fp32 [8192][2048].
__global__ __launch_bounds__(256,2) void gemm_proj(
    const u16* __restrict__ Y, const u16* __restrict__ Wt, const float* __restrict__ bias,
    float* __restrict__ outp)
{
  __shared__ u16 As[128*32];
  __shared__ u16 Bs[128*32];
  const int t = threadIdx.x;
  const int bx = blockIdx.x, by = blockIdx.y;
  const int lane = t & 63, wv = t >> 6;
  const int lq = lane >> 4, ln = lane & 15;
  const int wm = wv >> 1, wn = wv & 1;

  // A via glds: chunk c -> row c>>2 (global m), k-sub c&3
  const int c0 = t, c1 = 256 + t;
  const int rA0 = by*128 + (c0 >> 2), rA1 = by*128 + (c1 >> 2);
  const u16* Ya0 = Y + ((size_t)((rA0 >> 10)*NH)*T_ + (rA0 & 1023))*HD;
  const u16* Ya1 = Y + ((size_t)((rA1 >> 10)*NH)*T_ + (rA1 & 1023))*HD;
  const int kc0 = (c0 & 3)*8, kc1 = (c1 & 3)*8;
  const u16* AsW0 = &As[(wv*64)*8];
  const u16* AsW1 = &As[(256 + wv*64)*8];

  const u16* Bp0 = Wt + (size_t)(bx*128 + (c0 >> 2))*2048 + (c0 & 3)*8;
  const u16* Bp1 = Wt + (size_t)(bx*128 + (c1 >> 2))*2048 + (c1 & 3)*8;
  const u16* BsW0 = &Bs[(wv*64)*8];
  const u16* BsW1 = &Bs[(256 + wv*64)*8];

  const f32x4 fz = {0.f,0.f,0.f,0.f};
  f32x4 acc[4][4];
#pragma unroll
  for (int i=0;i<4;i++)
#pragma unroll
    for (int j=0;j<4;j++) acc[i][j] = fz;

  for (int kt = 0; kt < 64; ++kt){
    __syncthreads();
    {
      const int k0 = kt*32 + kc0, k1 = kt*32 + kc1;    // head h = k>>7, d = k&127
      glds16(Ya0 + (size_t)(k0 >> 7)*(T_*HD) + (k0 & 127), AsW0);
      glds16(Ya1 + (size_t)(k1 >> 7)*(T_*HD) + (k1 & 127), AsW1);
      glds16(Bp0, BsW0);
      glds16(Bp1, BsW1);
      Bp0 += 32; Bp1 += 32;
    }
    __syncthreads();
    bf16x8 af[4], bf[4];
#pragma unroll
    for (int i=0;i<4;i++) af[i] = ldfrag(&As[(wm*64 + i*16 + ln)*32 + lq*8]);
#pragma unroll
    for (int j=0;j<4;j++) bf[j] = ldfrag(&Bs[(wn*64 + j*16 + ln)*32 + lq*8]);
#pragma unroll
    for (int i=0;i<4;i++)
#pragma unroll
      for (int j=0;j<4;j++)
        acc[i][j] = __builtin_amdgcn_mfma_f32_16x16x32_bf16(af[i], bf[j], acc[i][j], 0,0,0);
  }

  float* op = outp + (size_t)(by*128)*2048 + bx*128;
#pragma unroll
  for (int j=0;j<4;j++){
    const float bv = bias[bx*128 + wn*64 + j*16 + ln];
    const int n = wn*64 + j*16 + ln;
#pragma unroll
    for (int i=0;i<4;i++){
      const int m0 = wm*64 + i*16 + lq*4;
#pragma unroll
      for (int r=0;r<4;r++)
        op[(size_t)(m0 + r)*2048 + n] = acc[i][j][r] + bv;
    }
  }
}

// ---------------- flash attention. qy: Q in, y out (same buffer, block-disjoint
// tiles). k,v bf16 [BH][T][HD]; V transposed to [d][key] in LDS during staging.
__global__ __launch_bounds__(256,2) void attn_fwd(
    u16* qy, const u16* __restrict__ kk, const u16* __restrict__ vv)
{
  __shared__ u16 Ks[64*128];                   // [key][d]
  __shared__ u16 Vt[128*64];                   // [d][key]
  __shared__ u16 Ps[4*32*64];                  // per-wave P strip
  const int qt = blockIdx.x, bh = blockIdx.y;
  const int t = threadIdx.x;
  const int lane = t & 63, wv = t >> 6;
  const int lq = lane >> 4, ln = lane & 15;

  bf16x8 qf[2][4];                             // A-frag: m=lane&15, k=quad*8+j
#pragma unroll
  for (int i=0;i<2;i++)
#pragma unroll
    for (int kc=0;kc<4;kc++){
      int qrow = qt*128 + wv*32 + i*16 + ln;
      qf[i][kc] = ldfrag(&qy[((size_t)bh*T_ + qrow)*HD + kc*32 + lq*8]);
    }

  const f32x4 fz = {0.f,0.f,0.f,0.f};
  f32x4 o[2][8];
#pragma unroll
  for (int i=0;i<2;i++)
#pragma unroll
    for (int jd=0;jd<8;jd++) o[i][jd] = fz;
  float mi[2][4], li[2][4];
#pragma unroll
  for (int i=0;i<2;i++)
#pragma unroll
    for (int r=0;r<4;r++){ mi[i][r] = -1e30f; li[i][r] = 0.f; }

  const float scale = 0.08838834764831843f;    // 1/sqrt(128)
  const int kr = t & 63, dbase = (t >> 6)*32;  // V-transpose stage mapping
  const int nkt = 2*qt + 2;                    // causal: keys < (qt+1)*128
  for (int kt = 0; kt < nkt; ++kt){
    uint4 kreg[4];
    uint4 vreg[4];
    const uint4* ksrc = (const uint4*)(kk + ((size_t)bh*T_ + kt*64)*HD);
#pragma unroll
    for (int ii=0; ii<4; ++ii) kreg[ii] = ksrc[t + ii*256];
#pragma unroll
    for (int ch=0; ch<4; ++ch)
      vreg[ch] = *(const uint4*)&vv[((size_t)bh*T_ + kt*64 + kr)*HD + dbase + ch*8];
    __syncthreads();                           // prior iter done reading Ks/Vt
    uint4* kdst = (uint4*)Ks;
#pragma unroll
    for (int ii=0; ii<4; ++ii) kdst[t + ii*256] = kreg[ii];
#pragma unroll
    for (int ch=0; ch<4; ++ch){
      const u16* e = (const u16*)&vreg[ch];
#pragma unroll
      for (int j=0; j<8; ++j)
        Vt[(dbase + ch*8 + j)*64 + kr] = e[j];  // banks = kr>>1: 2-way, free
    }
    __syncthreads();

    // S = Q K^T
    f32x4 s[2][4];
#pragma unroll
    for (int i=0;i<2;i++)
#pragma unroll
      for (int j=0;j<4;j++) s[i][j] = fz;
#pragma unroll
    for (int j=0;j<4;j++){
      bf16x8 kf[4];                            // B-frag: n=key, k=d
#pragma unroll
      for (int kc=0;kc<4;kc++) kf[kc] = ldfrag(&Ks[(j*16 + ln)*128 + kc*32 + lq*8]);
#pragma unroll
      for (int i=0;i<2;i++)
#pragma unroll
        for (int kc=0;kc<4;kc++)
          s[i][j] = __builtin_amdgcn_mfma_f32_16x16x32_bf16(qf[i][kc], kf[kc], s[i][j], 0,0,0);
    }

    // scale + causal mask (C/D: row=quad*4+r, col=lane&15)
#pragma unroll
    for (int i=0;i<2;i++)
#pragma unroll
      for (int j=0;j<4;j++)
#pragma unroll
        for (int r=0;r<4;r++){
          int qg = qt*128 + wv*32 + i*16 + lq*4 + r;
          int kg = kt*64 + j*16 + ln;
          float sv = s[i][j][r]*scale;
          s[i][j][r] = (kg > qg) ? -1e30f : sv;
        }

    // online softmax (row = (i,r); 64 cols = 4 j x 16 lanes of same quad)
#pragma unroll
    for (int i=0;i<2;i++)
#pragma unroll
      for (int r=0;r<4;r++){
        float mx = fmaxf(fmaxf(s[i][0][r], s[i][1][r]), fmaxf(s[i][2][r], s[i][3][r]));
        mx = fmaxf(mx, __shfl_xor(mx, 1));
        mx = fmaxf(mx, __shfl_xor(mx, 2));
        mx = fmaxf(mx, __shfl_xor(mx, 4));
        mx = fmaxf(mx, __shfl_xor(mx, 8));
        float mnew = fmaxf(mi[i][r], mx);
        float alpha = __expf(mi[i][r] - mnew);
        float rs = 0.f;
#pragma unroll
        for (int j=0;j<4;j++){
          float p = __expf(s[i][j][r] - mnew);
          s[i][j][r] = p; rs += p;
        }
        rs += __shfl_xor(rs, 1); rs += __shfl_xor(rs, 2);
        rs += __shfl_xor(rs, 4); rs += __shfl_xor(rs, 8);
        li[i][r] = li[i][r]*alpha + rs;
        mi[i][r] = mnew;
#pragma unroll
        for (int jd=0;jd<8;jd++) o[i][jd][r] *= alpha;
      }

    // P: C-layout -> per-wave LDS strip -> A-layout frags
#pragma unroll
    for (int i=0;i<2;i++)
#pragma unroll
      for (int j=0;j<4;j++)
#pragma unroll
        for (int r=0;r<4;r++)
          Ps[wv*2048 + (i*16 + lq*4 + r)*64 + j*16 + ln] = f2b(s[i][j][r]);

    bf16x8 pf[2][2];
#pragma unroll
    for (int i=0;i<2;i++)
#pragma unroll
      for (int kc=0;kc<2;kc++)
        pf[i][kc] = ldfrag(&Ps[wv*2048 + (i*16 + ln)*64 + kc*32 + lq*8]);
#pragma unroll
    for (int jd=0;jd<8;jd++)
#pragma unroll
      for (int kc=0;kc<2;kc++){
        bf16x8 vf = ldfrag(&Vt[(jd*16 + ln)*64 + kc*32 + lq*8]);
#pragma unroll
        for (int i=0;i<2;i++)
          o[i][jd] = __builtin_amdgcn_mfma_f32_16x16x32_bf16(pf[i][kc], vf, o[i][jd], 0,0,0);
      }
  }

  // epilogue: y over own Q tile, head-major [BH][T][HD]
#pragma unroll
  for (int i=0;i<2;i++)
#pragma unroll
    for (int r=0;r<4;r++){
      float inv = 1.f / li[i][r];
      int row = qt*128 + wv*32 + i*16 + lq*4 + r;
#pragma unroll
      for (int jd=0;jd<8;jd++)
        qy[((size_t)bh*T_ + row)*HD + jd*16 + ln] = f2b(o[i][jd][r] * inv);
    }
}

extern "C" void kernel_launch(void* const* d_in, const int* in_sizes, int n_in,
                              void* d_out, int out_size, void* d_ws, size_t ws_size,
                              hipStream_t stream)
{
  const float* x      = (const float*)d_in[0];   // [8192][2048] fp32
  const float* W_attn = (const float*)d_in[1];   // [2048][6144] fp32
  const float* b_attn = (const float*)d_in[2];   // [6144] fp32
  const float* W_proj = (const float*)d_in[3];   // [2048][2048] fp32
  const float* b_proj = (const float*)d_in[4];   // [2048] fp32
  float* out = (float*)d_out;                    // [8192][2048] fp32

  u16* Wat = (u16*)d_ws;                         // [6144][2048] bf16 = W_attn^T
  u16* Wpt = Wat + (size_t)6144*2048;            // [2048][2048] bf16 = W_proj^T
  u16* qb  = Wpt + (size_t)2048*2048;            // Q bf16, then y bf16
  u16* kb  = (u16*)d_out;                        // K bf16 (d_out low half)
  u16* vb  = kb + (size_t)BH*T_*HD;              // V bf16 (d_out high half)

  hipLaunchKernelGGL(transpose_cvt, dim3(96,32,1), dim3(256,1,1), 0, stream,
                     W_attn, Wat, 2048, 6144);
  hipLaunchKernelGGL(transpose_cvt, dim3(32,32,1), dim3(256,1,1), 0, stream,
                     W_proj, Wpt, 2048, 2048);
  hipLaunchKernelGGL(gemm_qkv, dim3(48,64,1), dim3(256,1,1), 0, stream,
                     x, Wat, b_attn, qb, kb, vb);
  hipLaunchKernelGGL(attn_fwd, dim3(8,BH,1), dim3(256,1,1), 0, stream,
                     qb, kb, vb);
  hipLaunchKernelGGL(gemm_proj, dim3(16,64,1), dim3(256,1,1), 0, stream,
                     qb, Wpt, b_proj, out);
}

// Round 6
// 699.040 us; speedup vs baseline: 1.3987x; 1.1224x over previous
//
#include <hip/hip_runtime.h>
#include <hip/hip_bf16.h>

// CausalSelfAttention: B=8 T=1024 C=2048 NH=16 HD=128. FP32 I/O, bf16 MFMA.
// R6: if ws >= 96 MiB, pre-convert x->bf16 and run full-m97 QKV GEMM (both
// operands via global_load_lds dwordx4); else fall back to R5's fp32-A path.
// Attention q-tiles launched heavy-first (qt = 7 - blockIdx.x).
// ws: Wat^T 24M | Wpt^T 8M | Q 32M (y overwrites Q after attn) | [xb 32M].
// d_out: K bf16 | V bf16 until proj GEMM overwrites with fp32 result.

typedef unsigned short u16;
typedef __bf16 bf16x8 __attribute__((ext_vector_type(8)));
typedef float f32x4 __attribute__((ext_vector_type(4)));

#define B_ 8
#define T_ 1024
#define C_ 2048
#define NH 16
#define HD 128
#define BH (B_*NH)

__device__ __forceinline__ u16 f2b(float f){
  __bf16 h = (__bf16)f; return __builtin_bit_cast(u16, h);   // RNE
}
__device__ __forceinline__ unsigned pk2(float x, float y){
  return (unsigned)f2b(x) | ((unsigned)f2b(y) << 16);
}
__device__ __forceinline__ bf16x8 ldfrag(const u16* p){
  uint4 u = *(const uint4*)p; return __builtin_bit_cast(bf16x8, u);
}
__device__ __forceinline__ void glds16(const u16* g, const u16* l){
  __builtin_amdgcn_global_load_lds(
      (const __attribute__((address_space(1))) void*)g,
      (__attribute__((address_space(3))) void*)l, 16, 0, 0);
}

// ---------------- fp32 -> bf16 pack, n4 = n/4 ------------------------------
__global__ __launch_bounds__(256) void cvt_bf16(
    const float4* __restrict__ in, ushort4* __restrict__ outp, int n4)
{
  int i = blockIdx.x*256 + threadIdx.x;
  const int stride = gridDim.x*256;
  for (; i < n4; i += stride){
    float4 f = in[i];
    ushort4 o; o.x = f2b(f.x); o.y = f2b(f.y); o.z = f2b(f.z); o.w = f2b(f.w);
    outp[i] = o;
  }
}

// ---------------- W fp32 [R][C] -> bf16 W^T [C][R], 64x64 tiles --------------
__global__ __launch_bounds__(256) void transpose_cvt(
    const float* __restrict__ in, u16* __restrict__ outp, int R, int C)
{
  __shared__ u16 tile[64][65];
  const int t = threadIdx.x;
  const int r0 = blockIdx.y * 64, c0 = blockIdx.x * 64;
#pragma unroll
  for (int ii = 0; ii < 16; ++ii){
    int idx = t + ii*256; int r = idx >> 6, c = idx & 63;
    tile[r][c] = f2b(in[(size_t)(r0 + r)*C + c0 + c]);
  }
  __syncthreads();
#pragma unroll
  for (int ii = 0; ii < 16; ++ii){
    int idx = t + ii*256; int r = idx >> 6, c = idx & 63;
    outp[(size_t)(c0 + r)*R + r0 + c] = tile[c][r];
  }
}

// ---------------- QKV epilogue (shared): scatter Q/K/V [BH][T][HD] -----------
__device__ __forceinline__ void qkv_epilogue(
    const f32x4 acc[4][4], const float* bias, int bx, int by,
    int wm, int wn, int lq, int ln,
    u16* qb, u16* kb, u16* vb)
{
  const int tensor = bx >> 4, h = bx & 15, b = by >> 3, t0 = (by & 7)*128;
  u16* tb = tensor==0 ? qb : (tensor==1 ? kb : vb);
  u16* op = tb + ((size_t)(b*NH + h)*T_ + t0)*HD;
#pragma unroll
  for (int j=0;j<4;j++){
    const float bv = bias[bx*128 + wn*64 + j*16 + ln];
    const int n = wn*64 + j*16 + ln;
#pragma unroll
    for (int i=0;i<4;i++){
      const int m0 = wm*64 + i*16 + lq*4;      // C/D: row = quad*4 + reg
#pragma unroll
      for (int r=0;r<4;r++)
        op[(size_t)(m0 + r)*HD + n] = f2b(acc[i][j][r] + bv);
    }
  }
}

// ---------------- QKV GEMM, m97 path: A = xb bf16 [8192][2048] (glds);
// B = Wat^T bf16 [6144][2048] (glds). ---------------------------------------
__global__ __launch_bounds__(256,2) void gemm_qkv_bb(
    const u16* __restrict__ Xb, const u16* __restrict__ Wt, const float* __restrict__ bias,
    u16* __restrict__ qb, u16* __restrict__ kb, u16* __restrict__ vb)
{
  __shared__ u16 As[128*32];                   // [m][k]
  __shared__ u16 Bs[128*32];                   // [n][k]
  const int t = threadIdx.x;
  const int bx = blockIdx.x, by = blockIdx.y;
  const int lane = t & 63, wv = t >> 6;
  const int lq = lane >> 4, ln = lane & 15;
  const int wm = wv >> 1, wn = wv & 1;

  // chunk c = pass*256 + t -> row c>>2, k-sub (c&3)*8; LDS dest = base+lane*16
  const int c0 = t, c1 = 256 + t;
  const u16* Ap0 = Xb + (size_t)(by*128 + (c0 >> 2))*2048 + (c0 & 3)*8;
  const u16* Ap1 = Xb + (size_t)(by*128 + (c1 >> 2))*2048 + (c1 & 3)*8;
  const u16* Bp0 = Wt + (size_t)(bx*128 + (c0 >> 2))*2048 + (c0 & 3)*8;
  const u16* Bp1 = Wt + (size_t)(bx*128 + (c1 >> 2))*2048 + (c1 & 3)*8;
  const u16* AsW0 = &As[(wv*64)*8];
  const u16* AsW1 = &As[(256 + wv*64)*8];
  const u16* BsW0 = &Bs[(wv*64)*8];
  const u16* BsW1 = &Bs[(256 + wv*64)*8];

  const f32x4 fz = {0.f,0.f,0.f,0.f};
  f32x4 acc[4][4];
#pragma unroll
  for (int i=0;i<4;i++)
#pragma unroll
    for (int j=0;j<4;j++) acc[i][j] = fz;

  for (int kt = 0; kt < 64; ++kt){
    __syncthreads();
    glds16(Ap0, AsW0); glds16(Ap1, AsW1);
    glds16(Bp0, BsW0); glds16(Bp1, BsW1);
    Ap0 += 32; Ap1 += 32; Bp0 += 32; Bp1 += 32;
    __syncthreads();
    bf16x8 af[4], bf[4];
#pragma unroll
    for (int i=0;i<4;i++) af[i] = ldfrag(&As[(wm*64 + i*16 + ln)*32 + lq*8]);
#pragma unroll
    for (int j=0;j<4;j++) bf[j] = ldfrag(&Bs[(wn*64 + j*16 + ln)*32 + lq*8]);
#pragma unroll
    for (int i=0;i<4;i++)
#pragma unroll
      for (int j=0;j<4;j++)
        acc[i][j] = __builtin_amdgcn_mfma_f32_16x16x32_bf16(af[i], bf[j], acc[i][j], 0,0,0);
  }
  qkv_epilogue(acc, bias, bx, by, wm, wn, lq, ln, qb, kb, vb);
}

// ---------------- QKV GEMM, fallback: A = x fp32 (cvt in staging). ----------
__global__ __launch_bounds__(256,2) void gemm_qkv_f32(
    const float* __restrict__ X, const u16* __restrict__ Wt, const float* __restrict__ bias,
    u16* __restrict__ qb, u16* __restrict__ kb, u16* __restrict__ vb)
{
  __shared__ u16 As[128*32];
  __shared__ u16 Bs[128*32];
  const int t = threadIdx.x;
  const int bx = blockIdx.x, by = blockIdx.y;
  const int lane = t & 63, wv = t >> 6;
  const int lq = lane >> 4, ln = lane & 15;
  const int wm = wv >> 1, wn = wv & 1;

  const int ar = t >> 1, ah = t & 1;
  const float* Ap = X + (size_t)(by*128 + ar)*2048 + ah*16;
  u16* AsW = &As[ar*32 + ah*16];

  const int c0 = t, c1 = 256 + t;
  const u16* Bp0 = Wt + (size_t)(bx*128 + (c0 >> 2))*2048 + (c0 & 3)*8;
  const u16* Bp1 = Wt + (size_t)(bx*128 + (c1 >> 2))*2048 + (c1 & 3)*8;
  const u16* BsW0 = &Bs[(wv*64)*8];
  const u16* BsW1 = &Bs[(256 + wv*64)*8];

  const f32x4 fz = {0.f,0.f,0.f,0.f};
  f32x4 acc[4][4];
#pragma unroll
  for (int i=0;i<4;i++)
#pragma unroll
    for (int j=0;j<4;j++) acc[i][j] = fz;

  for (int kt = 0; kt < 64; ++kt){
    float4 a0 = *(const float4*)(Ap);
    float4 a1 = *(const float4*)(Ap + 4);
    float4 a2 = *(const float4*)(Ap + 8);
    float4 a3 = *(const float4*)(Ap + 12);
    Ap += 32;
    __syncthreads();
    uint4 w0, w1;
    w0.x = pk2(a0.x,a0.y); w0.y = pk2(a0.z,a0.w);
    w0.z = pk2(a1.x,a1.y); w0.w = pk2(a1.z,a1.w);
    w1.x = pk2(a2.x,a2.y); w1.y = pk2(a2.z,a2.w);
    w1.z = pk2(a3.x,a3.y); w1.w = pk2(a3.z,a3.w);
    *(uint4*)(AsW) = w0; *(uint4*)(AsW + 8) = w1;
    glds16(Bp0, BsW0);
    glds16(Bp1, BsW1);
    Bp0 += 32; Bp1 += 32;
    __syncthreads();
    bf16x8 af[4], bf[4];
#pragma unroll
    for (int i=0;i<4;i++) af[i] = ldfrag(&As[(wm*64 + i*16 + ln)*32 + lq*8]);
#pragma unroll
    for (int j=0;j<4;j++) bf[j] = ldfrag(&Bs[(wn*64 + j*16 + ln)*32 + lq*8]);
#pragma unroll
    for (int i=0;i<4;i++)
#pragma unroll
      for (int j=0;j<4;j++)
        acc[i][j] = __builtin_amdgcn_mfma_f32_16x16x32_bf16(af[i], bf[j], acc[i][j], 0,0,0);
  }
  qkv_epilogue(acc, bias, bx, by, wm, wn, lq, ln, qb, kb, vb);
}

// ---------------- proj GEMM: A = y bf16 head-major [BH][T][HD] (glds);
// B = Wpt^T bf16 [2048][2048] (glds); out fp32 [8192][2048].
__global__ __launch_bounds__(256,2) void gemm_proj(
    const u16* __restrict__ Y, const u16* __restrict__ Wt, const float* __restrict__ bias,
    float* __restrict__ outp)
{
  __shared__ u16 As[128*32];
  __shared__ u16 Bs[128*32];
  const int t = threadIdx.x;
  const int bx = blockIdx.x, by = blockIdx.y;
  const int lane = t & 63, wv = t >> 6;
  const int lq = lane >> 4, ln = lane & 15;
  const int wm = wv >> 1, wn = wv & 1;

  const int c0 = t, c1 = 256 + t;
  const int rA0 = by*128 + (c0 >> 2), rA1 = by*128 + (c1 >> 2);
  const u16* Ya0 = Y + ((size_t)((rA0 >> 10)*NH)*T_ + (rA0 & 1023))*HD;
  const u16* Ya1 = Y + ((size_t)((rA1 >> 10)*NH)*T_ + (rA1 & 1023))*HD;
  const int kc0 = (c0 & 3)*8, kc1 = (c1 & 3)*8;
  const u16* AsW0 = &As[(wv*64)*8];
  const u16* AsW1 = &As[(256 + wv*64)*8];

  const u16* Bp0 = Wt + (size_t)(bx*128 + (c0 >> 2))*2048 + (c0 & 3)*8;
  const u16* Bp1 = Wt + (size_t)(bx*128 + (c1 >> 2))*2048 + (c1 & 3)*8;
  const u16* BsW0 = &Bs[(wv*64)*8];
  const u16* BsW1 = &Bs[(256 + wv*64)*8];

  const f32x4 fz = {0.f,0.f,0.f,0.f};
  f32x4 acc[4][4];
#pragma unroll
  for (int i=0;i<4;i++)
#pragma unroll
    for (int j=0;j<4;j++) acc[i][j] = fz;

  for (int kt = 0; kt < 64; ++kt){
    __syncthreads();
    {
      const int k0 = kt*32 + kc0, k1 = kt*32 + kc1;    // head = k>>7, d = k&127
      glds16(Ya0 + (size_t)(k0 >> 7)*(T_*HD) + (k0 & 127), AsW0);
      glds16(Ya1 + (size_t)(k1 >> 7)*(T_*HD) + (k1 & 127), AsW1);
      glds16(Bp0, BsW0);
      glds16(Bp1, BsW1);
      Bp0 += 32; Bp1 += 32;
    }
    __syncthreads();
    bf16x8 af[4], bf[4];
#pragma unroll
    for (int i=0;i<4;i++) af[i] = ldfrag(&As[(wm*64 + i*16 + ln)*32 + lq*8]);
#pragma unroll
    for (int j=0;j<4;j++) bf[j] = ldfrag(&Bs[(wn*64 + j*16 + ln)*32 + lq*8]);
#pragma unroll
    for (int i=0;i<4;i++)
#pragma unroll
      for (int j=0;j<4;j++)
        acc[i][j] = __builtin_amdgcn_mfma_f32_16x16x32_bf16(af[i], bf[j], acc[i][j], 0,0,0);
  }

  float* op = outp + (size_t)(by*128)*2048 + bx*128;
#pragma unroll
  for (int j=0;j<4;j++){
    const float bv = bias[bx*128 + wn*64 + j*16 + ln];
    const int n = wn*64 + j*16 + ln;
#pragma unroll
    for (int i=0;i<4;i++){
      const int m0 = wm*64 + i*16 + lq*4;
#pragma unroll
      for (int r=0;r<4;r++)
        op[(size_t)(m0 + r)*2048 + n] = acc[i][j][r] + bv;
    }
  }
}

// ---------------- flash attention. qy: Q in, y out (same buffer, block-disjoint
// tiles). k,v bf16 [BH][T][HD]; V transposed to [d][key] in LDS during staging.
// Heavy q-tiles first: qt = 7 - blockIdx.x.
__global__ __launch_bounds__(256,2) void attn_fwd(
    u16* qy, const u16* __restrict__ kk, const u16* __restrict__ vv)
{
  __shared__ u16 Ks[64*128];                   // [key][d]
  __shared__ u16 Vt[128*64];                   // [d][key]
  __shared__ u16 Ps[4*32*64];                  // per-wave P strip
  const int qt = 7 - blockIdx.x, bh = blockIdx.y;
  const int t = threadIdx.x;
  const int lane = t & 63, wv = t >> 6;
  const int lq = lane >> 4, ln = lane & 15;

  bf16x8 qf[2][4];                             // A-frag: m=lane&15, k=quad*8+j
#pragma unroll
  for (int i=0;i<2;i++)
#pragma unroll
    for (int kc=0;kc<4;kc++){
      int qrow = qt*128 + wv*32 + i*16 + ln;
      qf[i][kc] = ldfrag(&qy[((size_t)bh*T_ + qrow)*HD + kc*32 + lq*8]);
    }

  const f32x4 fz = {0.f,0.f,0.f,0.f};
  f32x4 o[2][8];
#pragma unroll
  for (int i=0;i<2;i++)
#pragma unroll
    for (int jd=0;jd<8;jd++) o[i][jd] = fz;
  float mi[2][4], li[2][4];
#pragma unroll
  for (int i=0;i<2;i++)
#pragma unroll
    for (int r=0;r<4;r++){ mi[i][r] = -1e30f; li[i][r] = 0.f; }

  const float scale = 0.08838834764831843f;    // 1/sqrt(128)
  const int kr = t & 63, dbase = (t >> 6)*32;  // V-transpose stage mapping
  const int nkt = 2*qt + 2;                    // causal: keys < (qt+1)*128
  for (int kt = 0; kt < nkt; ++kt){
    uint4 kreg[4];
    uint4 vreg[4];
    const uint4* ksrc = (const uint4*)(kk + ((size_t)bh*T_ + kt*64)*HD);
#pragma unroll
    for (int ii=0; ii<4; ++ii) kreg[ii] = ksrc[t + ii*256];
#pragma unroll
    for (int ch=0; ch<4; ++ch)
      vreg[ch] = *(const uint4*)&vv[((size_t)bh*T_ + kt*64 + kr)*HD + dbase + ch*8];
    __syncthreads();                           // prior iter done reading Ks/Vt
    uint4* kdst = (uint4*)Ks;
#pragma unroll
    for (int ii=0; ii<4; ++ii) kdst[t + ii*256] = kreg[ii];
#pragma unroll
    for (int ch=0; ch<4; ++ch){
      const u16* e = (const u16*)&vreg[ch];
#pragma unroll
      for (int j=0; j<8; ++j)
        Vt[(dbase + ch*8 + j)*64 + kr] = e[j];  // banks = kr>>1: 2-way, free
    }
    __syncthreads();

    // S = Q K^T
    f32x4 s[2][4];
#pragma unroll
    for (int i=0;i<2;i++)
#pragma unroll
      for (int j=0;j<4;j++) s[i][j] = fz;
#pragma unroll
    for (int j=0;j<4;j++){
      bf16x8 kf[4];                            // B-frag: n=key, k=d
#pragma unroll
      for (int kc=0;kc<4;kc++) kf[kc] = ldfrag(&Ks[(j*16 + ln)*128 + kc*32 + lq*8]);
#pragma unroll
      for (int i=0;i<2;i++)
#pragma unroll
        for (int kc=0;kc<4;kc++)
          s[i][j] = __builtin_amdgcn_mfma_f32_16x16x32_bf16(qf[i][kc], kf[kc], s[i][j], 0,0,0);
    }

    // scale + causal mask (C/D: row=quad*4+r, col=lane&15)
#pragma unroll
    for (int i=0;i<2;i++)
#pragma unroll
      for (int j=0;j<4;j++)
#pragma unroll
        for (int r=0;r<4;r++){
          int qg = qt*128 + wv*32 + i*16 + lq*4 + r;
          int kg = kt*64 + j*16 + ln;
          float sv = s[i][j][r]*scale;
          s[i][j][r] = (kg > qg) ? -1e30f : sv;
        }

    // online softmax (row = (i,r); 64 cols = 4 j x 16 lanes of same quad)
#pragma unroll
    for (int i=0;i<2;i++)
#pragma unroll
      for (int r=0;r<4;r++){
        float mx = fmaxf(fmaxf(s[i][0][r], s[i][1][r]), fmaxf(s[i][2][r], s[i][3][r]));
        mx = fmaxf(mx, __shfl_xor(mx, 1));
        mx = fmaxf(mx, __shfl_xor(mx, 2));
        mx = fmaxf(mx, __shfl_xor(mx, 4));
        mx = fmaxf(mx, __shfl_xor(mx, 8));
        float mnew = fmaxf(mi[i][r], mx);
        float alpha = __expf(mi[i][r] - mnew);
        float rs = 0.f;
#pragma unroll
        for (int j=0;j<4;j++){
          float p = __expf(s[i][j][r] - mnew);
          s[i][j][r] = p; rs += p;
        }
        rs += __shfl_xor(rs, 1); rs += __shfl_xor(rs, 2);
        rs += __shfl_xor(rs, 4); rs += __shfl_xor(rs, 8);
        li[i][r] = li[i][r]*alpha + rs;
        mi[i][r] = mnew;
#pragma unroll
        for (int jd=0;jd<8;jd++) o[i][jd][r] *= alpha;
      }

    // P: C-layout -> per-wave LDS strip -> A-layout frags
#pragma unroll
    for (int i=0;i<2;i++)
#pragma unroll
      for (int j=0;j<4;j++)
#pragma unroll
        for (int r=0;r<4;r++)
          Ps[wv*2048 + (i*16 + lq*4 + r)*64 + j*16 + ln] = f2b(s[i][j][r]);

    bf16x8 pf[2][2];
#pragma unroll
    for (int i=0;i<2;i++)
#pragma unroll
      for (int kc=0;kc<2;kc++)
        pf[i][kc] = ldfrag(&Ps[wv*2048 + (i*16 + ln)*64 + kc*32 + lq*8]);
#pragma unroll
    for (int jd=0;jd<8;jd++)
#pragma unroll
      for (int kc=0;kc<2;kc++){
        bf16x8 vf = ldfrag(&Vt[(jd*16 + ln)*64 + kc*32 + lq*8]);
#pragma unroll
        for (int i=0;i<2;i++)
          o[i][jd] = __builtin_amdgcn_mfma_f32_16x16x32_bf16(pf[i][kc], vf, o[i][jd], 0,0,0);
      }
  }

  // epilogue: y over own Q tile, head-major [BH][T][HD]
#pragma unroll
  for (int i=0;i<2;i++)
#pragma unroll
    for (int r=0;r<4;r++){
      float inv = 1.f / li[i][r];
      int row = qt*128 + wv*32 + i*16 + lq*4 + r;
#pragma unroll
      for (int jd=0;jd<8;jd++)
        qy[((size_t)bh*T_ + row)*HD + jd*16 + ln] = f2b(o[i][jd][r] * inv);
    }
}

extern "C" void kernel_launch(void* const* d_in, const int* in_sizes, int n_in,
                              void* d_out, int out_size, void* d_ws, size_t ws_size,
                              hipStream_t stream)
{
  const float* x      = (const float*)d_in[0];   // [8192][2048] fp32
  const float* W_attn = (const float*)d_in[1];   // [2048][6144] fp32
  const float* b_attn = (const float*)d_in[2];   // [6144] fp32
  const float* W_proj = (const float*)d_in[3];   // [2048][2048] fp32
  const float* b_proj = (const float*)d_in[4];   // [2048] fp32
  float* out = (float*)d_out;                    // [8192][2048] fp32

  u16* Wat = (u16*)d_ws;                         // [6144][2048] bf16 = W_attn^T
  u16* Wpt = Wat + (size_t)6144*2048;            // [2048][2048] bf16 = W_proj^T
  u16* qb  = Wpt + (size_t)2048*2048;            // Q bf16, then y bf16
  u16* xb  = qb  + (size_t)BH*T_*HD;             // x bf16 (only if ws >= 96 MiB)
  u16* kb  = (u16*)d_out;                        // K bf16 (d_out low half)
  u16* vb  = kb + (size_t)BH*T_*HD;              // V bf16 (d_out high half)

  const size_t need = ((size_t)6144*2048 + (size_t)2048*2048
                       + 2*(size_t)BH*T_*HD) * sizeof(u16);   // 96 MiB

  hipLaunchKernelGGL(transpose_cvt, dim3(96,32,1), dim3(256,1,1), 0, stream,
                     W_attn, Wat, 2048, 6144);
  hipLaunchKernelGGL(transpose_cvt, dim3(32,32,1), dim3(256,1,1), 0, stream,
                     W_proj, Wpt, 2048, 2048);
  if (ws_size >= need){
    hipLaunchKernelGGL(cvt_bf16, dim3(1024,1,1), dim3(256,1,1), 0, stream,
                       (const float4*)x, (ushort4*)xb, (B_*T_*C_)/4);
    hipLaunchKernelGGL(gemm_qkv_bb, dim3(48,64,1), dim3(256,1,1), 0, stream,
                       xb, Wat, b_attn, qb, kb, vb);
  } else {
    hipLaunchKernelGGL(gemm_qkv_f32, dim3(48,64,1), dim3(256,1,1), 0, stream,
                       x, Wat, b_attn, qb, kb, vb);
  }
  hipLaunchKernelGGL(attn_fwd, dim3(8,BH,1), dim3(256,1,1), 0, stream,
                     qb, kb, vb);
  hipLaunchKernelGGL(gemm_proj, dim3(16,64,1), dim3(256,1,1), 0, stream,
                     qb, Wpt, b_proj, out);
}